// Round 1
// baseline (167.316 us; speedup 1.0000x reference)
//
#include <hip/hip_runtime.h>
#include <hip/hip_bf16.h>
#include <stdint.h>

// Problem constants (SequentialMLP: E=8, H=1024, F=1024, T=16384, Tpe=2048)
#define T_TOK 16384
#define H_DIM 1024
#define F_DIM 1024
#define E_NUM 8
#define TPE   2048

typedef unsigned short u16;
typedef __attribute__((ext_vector_type(8))) short bf16x8;   // 8 bf16 (4 VGPRs)
typedef __attribute__((ext_vector_type(4))) float f32x4;    // MFMA accumulator
typedef __attribute__((ext_vector_type(8))) u16 u16x8;

__device__ __forceinline__ u16 f2bf(float x) {
  unsigned int u = __float_as_uint(x);
  u = (u + 0x7fffu + ((u >> 16) & 1u)) >> 16;   // RNE
  return (u16)u;
}

// async global->LDS, 16B per lane. LDS dest = wave-uniform base + lane*16.
#define GLD16(gp, lp)                                                          \
  __builtin_amdgcn_global_load_lds(                                            \
      (const __attribute__((address_space(1))) void*)(gp),                     \
      (__attribute__((address_space(3))) void*)(lp), 16, 0, 0)

// ---------------------------------------------------------------- prep pass
__global__ __launch_bounds__(256) void cvt_f32_bf16(
    const float* __restrict__ src, u16* __restrict__ dst, int n8) {
  int stride = gridDim.x * blockDim.x;
  for (int i = blockIdx.x * blockDim.x + threadIdx.x; i < n8; i += stride) {
    const float4* s = (const float4*)(src + (size_t)i * 8);
    float4 a = s[0], b = s[1];
    u16x8 o;
    o[0] = f2bf(a.x); o[1] = f2bf(a.y); o[2] = f2bf(a.z); o[3] = f2bf(a.w);
    o[4] = f2bf(b.x); o[5] = f2bf(b.y); o[6] = f2bf(b.z); o[7] = f2bf(b.w);
    *(u16x8*)(dst + (size_t)i * 8) = o;
  }
}

// batched [E][R][C] f32 -> [E][C][R] bf16 tiled transpose (64x64 tiles)
__global__ __launch_bounds__(256) void transpose_cvt(
    const float* __restrict__ src, u16* __restrict__ dst, int R, int C) {
  __shared__ float tile[64][65];
  int nCt = C >> 6, nRt = R >> 6;
  int per = nCt * nRt;
  int b = blockIdx.x;
  int e = b / per;
  int r2 = b - e * per;
  int rt = r2 / nCt, ct = r2 - rt * nCt;
  const float* s = src + (size_t)e * R * C + (size_t)(rt << 6) * C + (ct << 6);
  int t = threadIdx.x;
  int lr = t >> 4, lc = (t & 15) << 2;
#pragma unroll
  for (int i = 0; i < 4; i++) {
    float4 v = *(const float4*)(s + (size_t)(lr + i * 16) * C + lc);
    tile[lr + i * 16][lc + 0] = v.x;
    tile[lr + i * 16][lc + 1] = v.y;
    tile[lr + i * 16][lc + 2] = v.z;
    tile[lr + i * 16][lc + 3] = v.w;
  }
  __syncthreads();
  u16* d = dst + (size_t)e * C * R + (size_t)(ct << 6) * R + (rt << 6);
  int orow = t >> 2, ok = (t & 3) << 4;
  u16x8 o0, o1;
#pragma unroll
  for (int i = 0; i < 8; i++) o0[i] = f2bf(tile[ok + i][orow]);
#pragma unroll
  for (int i = 0; i < 8; i++) o1[i] = f2bf(tile[ok + 8 + i][orow]);
  *(u16x8*)(d + (size_t)orow * R + ok) = o0;
  *(u16x8*)(d + (size_t)orow * R + ok + 8) = o1;
}

// ---------------------------------------------------------------- GEMM1+GLU
// Per block: 128 tokens x (128 gate cols + 128 lin cols), K=H=1024, BK=64.
// LDS: A tile [128][64] bf16 (16KB) + B tile [256][64] bf16 (32KB), both with
// byte ^= ((row&7)<<4) XOR swizzle applied via pre-swizzled global source.
__global__ __launch_bounds__(512, 1) void gemm1_act(
    const u16* __restrict__ xbf, const u16* __restrict__ w1t,
    const float* __restrict__ b1, const float* __restrict__ probs,
    u16* __restrict__ abf) {
  __shared__ char sm[49152];
  const int tid = threadIdx.x;
  const int lane = tid & 63;
  const int wid = tid >> 6;
  const int wm = wid >> 2, wn = wid & 3;
  const int bid = blockIdx.x;
  const int e = bid >> 7;
  const int mt = (bid >> 3) & 15;
  const int ct = bid & 7;
  const int tokBase = e * TPE + mt * 128;
  const int c0 = ct * 128;

  // staging source pointers (inverse-swizzled global addresses, linear LDS)
  const u16* ag[2]; char* al[2];
#pragma unroll
  for (int q = 0; q < 2; q++) {
    int lin = q * 8192 + wid * 1024 + lane * 16;
    int lg = lin ^ (((lin >> 7) & 7) << 4);
    int row = lg >> 7, kk = (lg & 127) >> 1;
    ag[q] = xbf + (size_t)(tokBase + row) * H_DIM + kk;
    al[q] = sm + lin;
  }
  const u16* bg[4]; char* bl[4];
#pragma unroll
  for (int q = 0; q < 4; q++) {
    int lin = q * 8192 + wid * 1024 + lane * 16;
    int lg = lin ^ (((lin >> 7) & 7) << 4);
    int nn = lg >> 7, kk = (lg & 127) >> 1;
    // B row nn -> W1t row: alternate 32-blocks gate/lin so each wave owns
    // matching gate+lin fragments. col_f = c0 + (nn>>6)*32 + (nn&31).
    int col = ((((nn >> 5) & 1)) << 10) + c0 + ((nn >> 6) << 5) + (nn & 31);
    bg[q] = w1t + (size_t)(e * 2 * F_DIM + col) * H_DIM + kk;
    bl[q] = sm + 16384 + lin;
  }

  const int lrow = lane & 15, lkhi = lane >> 4;
  int aoff[4], boff[4], koff[2];
#pragma unroll
  for (int i = 0; i < 4; i++) aoff[i] = (wm * 64 + i * 16 + lrow) * 128;
#pragma unroll
  for (int j = 0; j < 4; j++) boff[j] = 16384 + (wn * 64 + j * 16 + lrow) * 128;
#pragma unroll
  for (int ks = 0; ks < 2; ks++)
    koff[ks] = ((ks << 6) | (lkhi << 4)) ^ ((lane & 7) << 4);

  f32x4 acc[4][4];
#pragma unroll
  for (int i = 0; i < 4; i++)
#pragma unroll
    for (int j = 0; j < 4; j++) acc[i][j] = f32x4{0.f, 0.f, 0.f, 0.f};

  for (int kt = 0; kt < H_DIM / 64; ++kt) {
    __syncthreads();
    GLD16(ag[0], al[0]); GLD16(ag[1], al[1]);
    GLD16(bg[0], bl[0]); GLD16(bg[1], bl[1]);
    GLD16(bg[2], bl[2]); GLD16(bg[3], bl[3]);
    asm volatile("s_waitcnt vmcnt(0)" ::: "memory");
    __syncthreads();
#pragma unroll
    for (int ks = 0; ks < 2; ++ks) {
      bf16x8 afr[4], bfr[4];
#pragma unroll
      for (int i = 0; i < 4; i++)
        afr[i] = *(const bf16x8*)(sm + aoff[i] + koff[ks]);
#pragma unroll
      for (int j = 0; j < 4; j++)
        bfr[j] = *(const bf16x8*)(sm + boff[j] + koff[ks]);
#pragma unroll
      for (int i = 0; i < 4; i++)
#pragma unroll
        for (int j = 0; j < 4; j++)
          acc[i][j] = __builtin_amdgcn_mfma_f32_16x16x32_bf16(
              afr[i], bfr[j], acc[i][j], 0, 0, 0);
    }
#pragma unroll
    for (int q = 0; q < 2; q++) ag[q] += 64;
#pragma unroll
    for (int q = 0; q < 4; q++) bg[q] += 64;
  }

  // epilogue: a = silu(gate + b1g) * (lin + b1l + 1) * p, write bf16
#pragma unroll
  for (int jj = 0; jj < 2; ++jj) {
    int cf = c0 + wn * 32 + jj * 16 + lrow;
    float gb = b1[e * 2 * F_DIM + cf];
    float lb = b1[e * 2 * F_DIM + F_DIM + cf];
#pragma unroll
    for (int i = 0; i < 4; i++) {
      int trow = tokBase + wm * 64 + i * 16 + lkhi * 4;
#pragma unroll
      for (int r = 0; r < 4; r++) {
        float g = acc[i][jj][r] + gb;
        float l = acc[i][jj + 2][r] + lb + 1.0f;
        float p = probs[trow + r];
        float sig = 1.0f / (1.0f + __expf(-g));
        float av = g * sig * l * p;
        abf[(size_t)(trow + r) * F_DIM + cf] = f2bf(av);
      }
    }
  }
}

// ---------------------------------------------------------------- GEMM2
// Per block: 128 tokens x 256 H-cols, K=F=1024, BK=64. Same staging scheme.
__global__ __launch_bounds__(512, 1) void gemm2(
    const u16* __restrict__ abf, const u16* __restrict__ w2t,
    const float* __restrict__ b2, float* __restrict__ out) {
  __shared__ char sm[49152];
  const int tid = threadIdx.x;
  const int lane = tid & 63;
  const int wid = tid >> 6;
  const int wm = wid >> 2, wn = wid & 3;
  const int bid = blockIdx.x;
  const int e = bid >> 6;
  const int mt = (bid >> 2) & 15;
  const int nt = bid & 3;
  const int tokBase = e * TPE + mt * 128;
  const int h0 = nt * 256;

  const u16* ag[2]; char* al[2];
#pragma unroll
  for (int q = 0; q < 2; q++) {
    int lin = q * 8192 + wid * 1024 + lane * 16;
    int lg = lin ^ (((lin >> 7) & 7) << 4);
    int row = lg >> 7, kk = (lg & 127) >> 1;
    ag[q] = abf + (size_t)(tokBase + row) * F_DIM + kk;
    al[q] = sm + lin;
  }
  const u16* bg[4]; char* bl[4];
#pragma unroll
  for (int q = 0; q < 4; q++) {
    int lin = q * 8192 + wid * 1024 + lane * 16;
    int lg = lin ^ (((lin >> 7) & 7) << 4);
    int nn = lg >> 7, kk = (lg & 127) >> 1;
    bg[q] = w2t + (size_t)(e * H_DIM + h0 + nn) * F_DIM + kk;
    bl[q] = sm + 16384 + lin;
  }

  const int lrow = lane & 15, lkhi = lane >> 4;
  int aoff[4], boff[4], koff[2];
#pragma unroll
  for (int i = 0; i < 4; i++) aoff[i] = (wm * 64 + i * 16 + lrow) * 128;
#pragma unroll
  for (int j = 0; j < 4; j++) boff[j] = 16384 + (wn * 64 + j * 16 + lrow) * 128;
#pragma unroll
  for (int ks = 0; ks < 2; ks++)
    koff[ks] = ((ks << 6) | (lkhi << 4)) ^ ((lane & 7) << 4);

  f32x4 acc[4][4];
#pragma unroll
  for (int i = 0; i < 4; i++)
#pragma unroll
    for (int j = 0; j < 4; j++) acc[i][j] = f32x4{0.f, 0.f, 0.f, 0.f};

  for (int kt = 0; kt < F_DIM / 64; ++kt) {
    __syncthreads();
    GLD16(ag[0], al[0]); GLD16(ag[1], al[1]);
    GLD16(bg[0], bl[0]); GLD16(bg[1], bl[1]);
    GLD16(bg[2], bl[2]); GLD16(bg[3], bl[3]);
    asm volatile("s_waitcnt vmcnt(0)" ::: "memory");
    __syncthreads();
#pragma unroll
    for (int ks = 0; ks < 2; ++ks) {
      bf16x8 afr[4], bfr[4];
#pragma unroll
      for (int i = 0; i < 4; i++)
        afr[i] = *(const bf16x8*)(sm + aoff[i] + koff[ks]);
#pragma unroll
      for (int j = 0; j < 4; j++)
        bfr[j] = *(const bf16x8*)(sm + boff[j] + koff[ks]);
#pragma unroll
      for (int i = 0; i < 4; i++)
#pragma unroll
        for (int j = 0; j < 4; j++)
          acc[i][j] = __builtin_amdgcn_mfma_f32_16x16x32_bf16(
              afr[i], bfr[j], acc[i][j], 0, 0, 0);
    }
#pragma unroll
    for (int q = 0; q < 2; q++) ag[q] += 64;
#pragma unroll
    for (int q = 0; q < 4; q++) bg[q] += 64;
  }

#pragma unroll
  for (int j = 0; j < 4; ++j) {
    int h = h0 + wn * 64 + j * 16 + lrow;
    float bb = b2[e * H_DIM + h];
#pragma unroll
    for (int i = 0; i < 4; i++) {
      int trow = tokBase + wm * 64 + i * 16 + lkhi * 4;
#pragma unroll
      for (int r = 0; r < 4; r++)
        out[(size_t)(trow + r) * H_DIM + h] = acc[i][j][r] + bb;
    }
  }
}

// ---------------------------------------------------------------- launch
extern "C" void kernel_launch(void* const* d_in, const int* in_sizes, int n_in,
                              void* d_out, int out_size, void* d_ws,
                              size_t ws_size, hipStream_t stream) {
  const float* x     = (const float*)d_in[0];
  // d_in[1] tokens_per_expert: uniform (T/E) by construction, unused
  const float* probs = (const float*)d_in[2];
  const float* W1    = (const float*)d_in[3];
  const float* b1    = (const float*)d_in[4];
  const float* W2    = (const float*)d_in[5];
  const float* b2    = (const float*)d_in[6];
  float* out = (float*)d_out;

  // workspace layout (bytes):
  //   xbf  [T,H]    bf16   33,554,432
  //   w1t  [E,2F,H] bf16   33,554,432
  //   w2t  [E,H,F]  bf16   16,777,216
  //   abf  [T,F]    bf16   33,554,432    total 117,440,512
  if (ws_size < 117440512u) return;  // insufficient scratch: bail (will fail validation loudly)
  char* ws = (char*)d_ws;
  u16* xbf = (u16*)(ws);
  u16* w1t = (u16*)(ws + 33554432);
  u16* w2t = (u16*)(ws + 67108864);
  u16* abf = (u16*)(ws + 83886080);

  cvt_f32_bf16<<<2048, 256, 0, stream>>>(x, xbf, (T_TOK * H_DIM) / 8);
  transpose_cvt<<<E_NUM * (2 * F_DIM / 64) * (H_DIM / 64), 256, 0, stream>>>(
      W1, w1t, H_DIM, 2 * F_DIM);
  transpose_cvt<<<E_NUM * (H_DIM / 64) * (F_DIM / 64), 256, 0, stream>>>(
      W2, w2t, F_DIM, H_DIM);
  gemm1_act<<<E_NUM * (TPE / 128) * (F_DIM / 128), 512, 0, stream>>>(
      xbf, w1t, b1, probs, abf);
  gemm2<<<E_NUM * (TPE / 128) * (H_DIM / 256), 512, 0, stream>>>(
      abf, w2t, b2, out);
}

// Round 2
// 153.877 us; speedup vs baseline: 1.0873x; 1.0873x over previous
//
#include <hip/hip_runtime.h>
#include <hip/hip_bf16.h>
#include <stdint.h>

// SequentialMLP: E=8, H=1024, F=1024, T=16384, Tpe=2048
#define T_TOK 16384
#define H_DIM 1024
#define F_DIM 1024
#define E_NUM 8
#define TPE   2048

typedef unsigned short u16;
typedef __attribute__((ext_vector_type(8))) short bf16x8;   // 8 bf16 (4 VGPRs)
typedef __attribute__((ext_vector_type(4))) float f32x4;    // MFMA accumulator
typedef __attribute__((ext_vector_type(8))) u16 u16x8;

__device__ __forceinline__ u16 f2bf(float x) {
  unsigned int u = __float_as_uint(x);
  u = (u + 0x7fffu + ((u >> 16) & 1u)) >> 16;   // RNE
  return (u16)u;
}

// async global->LDS, 16B per lane. LDS dest = wave-uniform base + lane*16.
#define GLD16(gp, lp)                                                          \
  __builtin_amdgcn_global_load_lds(                                            \
      (const __attribute__((address_space(1))) void*)(gp),                     \
      (__attribute__((address_space(3))) void*)(lp), 16, 0, 0)

// ================================================================= prep pass
// one launch: [0,2048) x f32->bf16 cvt, [2048,6144) W1 transpose,
// [6144,8192) W2 transpose.
__global__ __launch_bounds__(256) void prep(
    const float* __restrict__ x, const float* __restrict__ W1,
    const float* __restrict__ W2, u16* __restrict__ xbf,
    u16* __restrict__ w1t, u16* __restrict__ w2t) {
  __shared__ float tile[64][65];
  const int b = blockIdx.x;
  const int t = threadIdx.x;
  if (b < 2048) {
    const int n8 = (T_TOK * H_DIM) / 8;
    for (int i = b * 256 + t; i < n8; i += 2048 * 256) {
      const float4* s = (const float4*)(x + (size_t)i * 8);
      float4 a = s[0], c = s[1];
      u16x8 o;
      o[0] = f2bf(a.x); o[1] = f2bf(a.y); o[2] = f2bf(a.z); o[3] = f2bf(a.w);
      o[4] = f2bf(c.x); o[5] = f2bf(c.y); o[6] = f2bf(c.z); o[7] = f2bf(c.w);
      *(u16x8*)(xbf + (size_t)i * 8) = o;
    }
    return;
  }
  const float* src; u16* dst; int R, C, id;
  if (b < 6144) { src = W1; dst = w1t; R = H_DIM; C = 2 * F_DIM; id = b - 2048; }
  else          { src = W2; dst = w2t; R = F_DIM; C = H_DIM;     id = b - 6144; }
  int nCt = C >> 6, nRt = R >> 6;
  int per = nCt * nRt;
  int e = id / per;
  int r2 = id - e * per;
  int rt = r2 / nCt, ct = r2 - rt * nCt;
  const float* s = src + (size_t)e * R * C + (size_t)(rt << 6) * C + (ct << 6);
  int lr = t >> 4, lc = (t & 15) << 2;
#pragma unroll
  for (int i = 0; i < 4; i++) {
    float4 v = *(const float4*)(s + (size_t)(lr + i * 16) * C + lc);
    tile[lr + i * 16][lc + 0] = v.x;
    tile[lr + i * 16][lc + 1] = v.y;
    tile[lr + i * 16][lc + 2] = v.z;
    tile[lr + i * 16][lc + 3] = v.w;
  }
  __syncthreads();
  u16* d = dst + (size_t)e * C * R + (size_t)(ct << 6) * R + (rt << 6);
  int orow = t >> 2, ok = (t & 3) << 4;
  u16x8 o0, o1;
#pragma unroll
  for (int i = 0; i < 8; i++) o0[i] = f2bf(tile[ok + i][orow]);
#pragma unroll
  for (int i = 0; i < 8; i++) o1[i] = f2bf(tile[ok + 8 + i][orow]);
  *(u16x8*)(d + (size_t)orow * R + ok) = o0;
  *(u16x8*)(d + (size_t)orow * R + ok + 8) = o1;
}

// ====================================================== 8-phase 256x256 GEMM
// BM=BN=256, BK=64, 8 waves (2Mx4N), 512 thr. LDS 128KB:
//   A buf b: [b*32768, +32KB)  rows 0..255 x 64k, row stride 128B, XOR-swz
//   B buf b: [65536 + b*32768, +32KB)
// Swizzle byte ^= ((row&7)<<4) applied via inverse-swizzled GLOBAL source
// (linear LDS dest, rule 21) + swizzled ds_read offset.
// Per K-tile: 4 phases; phase mi does 16 MFMA (m=2mi..2mi+1 x n0-3 x ks0-1).
// B frags (8) read once at mi=0 and held; A frags (4) read per phase.
// Prefetch ledger (half = 2 loads/thr): p0/p1: t1.A  p2/p3: t0'.B
// p4/p5: t0'.A  p6/p7: t1'.B ; vmcnt(4) at end of p3 & p7 (counted, never 0
// in steady state). Regions are freed by the closing barrier of an earlier
// phase before any prefetch targets them (ledger in session notes).

#define DSA(b, mi)                                                             \
  _Pragma("unroll") for (int m2_ = 0; m2_ < 2; ++m2_)                          \
  _Pragma("unroll") for (int ks_ = 0; ks_ < 2; ++ks_)                          \
      aF[m2_][ks_] = *(const bf16x8*)(sm + (b) * 32768 + aRowBase +            \
                                      ((mi) * 2 + m2_) * 2048 + koff[ks_]);

#define DSB(b)                                                                 \
  _Pragma("unroll") for (int n_ = 0; n_ < 4; ++n_)                             \
  _Pragma("unroll") for (int ks_ = 0; ks_ < 2; ++ks_)                          \
      bF[n_][ks_] = *(const bf16x8*)(sm + 65536 + (b) * 32768 + bRowBase +     \
                                     n_ * 2048 + koff[ks_]);

#define MFMA16(mi)                                                             \
  _Pragma("unroll") for (int m2_ = 0; m2_ < 2; ++m2_)                          \
  _Pragma("unroll") for (int n_ = 0; n_ < 4; ++n_)                             \
  _Pragma("unroll") for (int ks_ = 0; ks_ < 2; ++ks_)                          \
      acc[(mi) * 2 + m2_][n_] = __builtin_amdgcn_mfma_f32_16x16x32_bf16(       \
          aF[m2_][ks_], bF[n_][ks_], acc[(mi) * 2 + m2_][n_], 0, 0, 0);

#define PF_A(db, q, d) GLD16(aP[q] + (d), sm + (db) * 32768 + (q) * 8192 + tid * 16)
#define PF_B(db, q, d) GLD16(bP[q] + (d), sm + 65536 + (db) * 32768 + (q) * 8192 + tid * 16)

#define PHASE(b, mi, PFC, WTC)                                                 \
  do {                                                                         \
    if ((mi) == 0) { DSB(b); }                                                 \
    DSA(b, mi);                                                                \
    PFC                                                                        \
    WTC                                                                        \
    __builtin_amdgcn_s_barrier();                                              \
    asm volatile("s_waitcnt lgkmcnt(0)" ::: "memory");                         \
    __builtin_amdgcn_sched_barrier(0);                                         \
    __builtin_amdgcn_s_setprio(1);                                             \
    MFMA16(mi);                                                                \
    __builtin_amdgcn_s_setprio(0);                                             \
    __builtin_amdgcn_s_barrier();                                              \
  } while (0)

#define KLOOP_BODY                                                             \
  /* prologue: t0 (B,A) then t1.B; wait t0 arrived, 4 loads in flight */       \
  PF_B(0, 0, 0); PF_B(0, 1, 0); PF_B(0, 2, 0); PF_B(0, 3, 0);                  \
  PF_A(0, 0, 0); PF_A(0, 1, 0); PF_A(0, 2, 0); PF_A(0, 3, 0);                  \
  PF_B(1, 0, 64); PF_B(1, 1, 64); PF_B(1, 2, 64); PF_B(1, 3, 64);              \
  asm volatile("s_waitcnt vmcnt(4)" ::: "memory");                             \
  __builtin_amdgcn_s_barrier();                                                \
  for (int it = 0; it < 7; ++it) {                                             \
    PHASE(0, 0, PF_A(1, 0, 64); PF_A(1, 1, 64);, );                            \
    PHASE(0, 1, PF_A(1, 2, 64); PF_A(1, 3, 64);, );                            \
    PHASE(0, 2, PF_B(0, 0, 128); PF_B(0, 1, 128);, );                          \
    PHASE(0, 3, PF_B(0, 2, 128); PF_B(0, 3, 128);,                             \
          asm volatile("s_waitcnt vmcnt(4)" ::: "memory"););                   \
    PHASE(1, 0, PF_A(0, 0, 128); PF_A(0, 1, 128);, );                          \
    PHASE(1, 1, PF_A(0, 2, 128); PF_A(0, 3, 128);, );                          \
    PHASE(1, 2, PF_B(1, 0, 192); PF_B(1, 1, 192);, );                          \
    PHASE(1, 3, PF_B(1, 2, 192); PF_B(1, 3, 192);,                             \
          asm volatile("s_waitcnt vmcnt(4)" ::: "memory"););                   \
    _Pragma("unroll") for (int q_ = 0; q_ < 4; ++q_) {                         \
      aP[q_] += 128; bP[q_] += 128;                                            \
    }                                                                          \
  }                                                                            \
  /* peeled last iter: only t1.A issues remain; drain fully */                 \
  PHASE(0, 0, PF_A(1, 0, 64); PF_A(1, 1, 64);, );                              \
  PHASE(0, 1, PF_A(1, 2, 64); PF_A(1, 3, 64);, );                              \
  PHASE(0, 2, , );                                                             \
  PHASE(0, 3, , asm volatile("s_waitcnt vmcnt(0)" ::: "memory"););             \
  PHASE(1, 0, , );                                                             \
  PHASE(1, 1, , );                                                             \
  PHASE(1, 2, , );                                                             \
  PHASE(1, 3, , );

// ---------------------------------------------------------------- GEMM1+GLU
__global__ __launch_bounds__(512, 2) void gemm1_8p(
    const u16* __restrict__ xbf, const u16* __restrict__ w1t,
    const float* __restrict__ b1, const float* __restrict__ probs,
    u16* __restrict__ abf) {
  extern __shared__ char sm[];
  const int tid = threadIdx.x;
  const int lane = tid & 63;
  const int wid = tid >> 6;
  const int wm = wid >> 2, wn = wid & 3;
  const int bid = blockIdx.x;
  const int e = bid & 7;          // expert -> XCD pinning (round-robin bid%8)
  const int inner = bid >> 3;
  const int mt = inner >> 3, ct = inner & 7;
  const int tokBase = e * TPE + mt * 256;
  const int c0 = ct * 128;
  const int lrow = lane & 15, lkhi = lane >> 4;

  const u16* aP[4]; const u16* bP[4];
#pragma unroll
  for (int q = 0; q < 4; ++q) {
    int lin = q * 8192 + tid * 16;
    int lg = lin ^ (((lin >> 7) & 7) << 4);   // inverse swizzle (involution)
    int row = lg >> 7, kk = (lg & 127) >> 1;
    aP[q] = xbf + (size_t)(tokBase + row) * H_DIM + kk;
    // B row nn: alternate 32-blocks gate/lin so each wave owns matching pairs
    int col = (((row >> 5) & 1) << 10) + c0 + ((row >> 6) << 5) + (row & 31);
    bP[q] = w1t + (size_t)(e * 2 * F_DIM + col) * H_DIM + kk;
  }
  const int aRowBase = (wm * 128 + lrow) * 128;
  const int bRowBase = (wn * 64 + lrow) * 128;
  int koff[2];
#pragma unroll
  for (int ks = 0; ks < 2; ++ks)
    koff[ks] = ((ks << 6) | (lkhi << 4)) ^ ((lane & 7) << 4);

  f32x4 acc[8][4];
#pragma unroll
  for (int i = 0; i < 8; ++i)
#pragma unroll
    for (int j = 0; j < 4; ++j) acc[i][j] = f32x4{0.f, 0.f, 0.f, 0.f};
  bf16x8 aF[2][2], bF[4][2];

  KLOOP_BODY

  // epilogue: a = silu(gate+b1g) * (lin+b1l+1) * p -> bf16
#pragma unroll
  for (int j = 0; j < 2; ++j) {
    int cf = c0 + wn * 32 + j * 16 + lrow;
    float gb = b1[e * 2 * F_DIM + cf];
    float lb = b1[e * 2 * F_DIM + F_DIM + cf];
#pragma unroll
    for (int i = 0; i < 8; ++i) {
      int trow = tokBase + wm * 128 + i * 16 + lkhi * 4;
#pragma unroll
      for (int r = 0; r < 4; ++r) {
        float g = acc[i][j][r] + gb;
        float l = acc[i][j + 2][r] + lb + 1.0f;
        float p = probs[trow + r];
        float sig = 1.0f / (1.0f + __expf(-g));
        abf[(size_t)(trow + r) * F_DIM + cf] = f2bf(g * sig * l * p);
      }
    }
  }
}

// ---------------------------------------------------------------- GEMM2
__global__ __launch_bounds__(512, 2) void gemm2_8p(
    const u16* __restrict__ abf, const u16* __restrict__ w2t,
    const float* __restrict__ b2, float* __restrict__ out) {
  extern __shared__ char sm[];
  const int tid = threadIdx.x;
  const int lane = tid & 63;
  const int wid = tid >> 6;
  const int wm = wid >> 2, wn = wid & 3;
  const int bid = blockIdx.x;
  const int e = bid & 7;
  const int inner = bid >> 3;
  const int mt = inner >> 2, nt = inner & 3;
  const int tokBase = e * TPE + mt * 256;
  const int h0 = nt * 256;
  const int lrow = lane & 15, lkhi = lane >> 4;

  const u16* aP[4]; const u16* bP[4];
#pragma unroll
  for (int q = 0; q < 4; ++q) {
    int lin = q * 8192 + tid * 16;
    int lg = lin ^ (((lin >> 7) & 7) << 4);
    int row = lg >> 7, kk = (lg & 127) >> 1;
    aP[q] = abf + (size_t)(tokBase + row) * F_DIM + kk;
    bP[q] = w2t + (size_t)(e * H_DIM + h0 + row) * F_DIM + kk;
  }
  const int aRowBase = (wm * 128 + lrow) * 128;
  const int bRowBase = (wn * 64 + lrow) * 128;
  int koff[2];
#pragma unroll
  for (int ks = 0; ks < 2; ++ks)
    koff[ks] = ((ks << 6) | (lkhi << 4)) ^ ((lane & 7) << 4);

  f32x4 acc[8][4];
#pragma unroll
  for (int i = 0; i < 8; ++i)
#pragma unroll
    for (int j = 0; j < 4; ++j) acc[i][j] = f32x4{0.f, 0.f, 0.f, 0.f};
  bf16x8 aF[2][2], bF[4][2];

  KLOOP_BODY

#pragma unroll
  for (int j = 0; j < 4; ++j) {
    int h = h0 + wn * 64 + j * 16 + lrow;
    float bb = b2[e * H_DIM + h];
#pragma unroll
    for (int i = 0; i < 8; ++i) {
      int trow = tokBase + wm * 128 + i * 16 + lkhi * 4;
#pragma unroll
      for (int r = 0; r < 4; ++r)
        out[(size_t)(trow + r) * H_DIM + h] = acc[i][j][r] + bb;
    }
  }
}

// ---------------------------------------------------------------- launch
extern "C" void kernel_launch(void* const* d_in, const int* in_sizes, int n_in,
                              void* d_out, int out_size, void* d_ws,
                              size_t ws_size, hipStream_t stream) {
  const float* x     = (const float*)d_in[0];
  // d_in[1] tokens_per_expert: uniform (T/E) by construction, unused
  const float* probs = (const float*)d_in[2];
  const float* W1    = (const float*)d_in[3];
  const float* b1    = (const float*)d_in[4];
  const float* W2    = (const float*)d_in[5];
  const float* b2    = (const float*)d_in[6];
  float* out = (float*)d_out;

  // workspace: xbf[T,H] 32MB | w1t[E,2F,H] 32MB | w2t[E,H,F] 16MB | abf 32MB
  if (ws_size < 117440512u) return;
  char* ws = (char*)d_ws;
  u16* xbf = (u16*)(ws);
  u16* w1t = (u16*)(ws + 33554432);
  u16* w2t = (u16*)(ws + 67108864);
  u16* abf = (u16*)(ws + 83886080);

  // 128KB dynamic LDS needs the attribute raised (idempotent, capture-safe)
  (void)hipFuncSetAttribute(reinterpret_cast<const void*>(gemm1_8p),
                            hipFuncAttributeMaxDynamicSharedMemorySize, 131072);
  (void)hipFuncSetAttribute(reinterpret_cast<const void*>(gemm2_8p),
                            hipFuncAttributeMaxDynamicSharedMemorySize, 131072);

  prep<<<8192, 256, 0, stream>>>(x, W1, W2, xbf, w1t, w2t);
  gemm1_8p<<<E_NUM * 8 * 8, 512, 131072, stream>>>(xbf, w1t, b1, probs, abf);
  gemm2_8p<<<E_NUM * 8 * 4, 512, 131072, stream>>>(abf, w2t, b2, out);
}

// Round 3
// 151.457 us; speedup vs baseline: 1.1047x; 1.0160x over previous
//
#include <hip/hip_runtime.h>
#include <hip/hip_bf16.h>
#include <stdint.h>

// SequentialMLP: E=8, H=1024, F=1024, T=16384, Tpe=2048
#define T_TOK 16384
#define H_DIM 1024
#define F_DIM 1024
#define E_NUM 8
#define TPE   2048

typedef unsigned short u16;
typedef __attribute__((ext_vector_type(8))) short bf16x8;   // 8 bf16 (4 VGPRs)
typedef __attribute__((ext_vector_type(4))) float f32x4;    // MFMA accumulator
typedef __attribute__((ext_vector_type(8))) u16 u16x8;

__device__ __forceinline__ u16 f2bf(float x) {
  unsigned int u = __float_as_uint(x);
  u = (u + 0x7fffu + ((u >> 16) & 1u)) >> 16;   // RNE
  return (u16)u;
}

// async global->LDS, 16B per lane. LDS dest = wave-uniform base + lane*16.
#define GLD16(gp, lp)                                                          \
  __builtin_amdgcn_global_load_lds(                                            \
      (const __attribute__((address_space(1))) void*)(gp),                     \
      (__attribute__((address_space(3))) void*)(lp), 16, 0, 0)

// ================================================================= prep pass
__global__ __launch_bounds__(256) void prep(
    const float* __restrict__ x, const float* __restrict__ W1,
    const float* __restrict__ W2, u16* __restrict__ xbf,
    u16* __restrict__ w1t, u16* __restrict__ w2t) {
  __shared__ float tile[64][65];
  const int b = blockIdx.x;
  const int t = threadIdx.x;
  if (b < 2048) {
    const int n8 = (T_TOK * H_DIM) / 8;
    for (int i = b * 256 + t; i < n8; i += 2048 * 256) {
      const float4* s = (const float4*)(x + (size_t)i * 8);
      float4 a = s[0], c = s[1];
      u16x8 o;
      o[0] = f2bf(a.x); o[1] = f2bf(a.y); o[2] = f2bf(a.z); o[3] = f2bf(a.w);
      o[4] = f2bf(c.x); o[5] = f2bf(c.y); o[6] = f2bf(c.z); o[7] = f2bf(c.w);
      *(u16x8*)(xbf + (size_t)i * 8) = o;
    }
    return;
  }
  const float* src; u16* dst; int R, C, id;
  if (b < 6144) { src = W1; dst = w1t; R = H_DIM; C = 2 * F_DIM; id = b - 2048; }
  else          { src = W2; dst = w2t; R = F_DIM; C = H_DIM;     id = b - 6144; }
  int nCt = C >> 6, nRt = R >> 6;
  int per = nCt * nRt;
  int e = id / per;
  int r2 = id - e * per;
  int rt = r2 / nCt, ct = r2 - rt * nCt;
  const float* s = src + (size_t)e * R * C + (size_t)(rt << 6) * C + (ct << 6);
  int lr = t >> 4, lc = (t & 15) << 2;
#pragma unroll
  for (int i = 0; i < 4; i++) {
    float4 v = *(const float4*)(s + (size_t)(lr + i * 16) * C + lc);
    tile[lr + i * 16][lc + 0] = v.x;
    tile[lr + i * 16][lc + 1] = v.y;
    tile[lr + i * 16][lc + 2] = v.z;
    tile[lr + i * 16][lc + 3] = v.w;
  }
  __syncthreads();
  u16* d = dst + (size_t)e * C * R + (size_t)(ct << 6) * R + (rt << 6);
  int orow = t >> 2, ok = (t & 3) << 4;
  u16x8 o0, o1;
#pragma unroll
  for (int i = 0; i < 8; i++) o0[i] = f2bf(tile[ok + i][orow]);
#pragma unroll
  for (int i = 0; i < 8; i++) o1[i] = f2bf(tile[ok + 8 + i][orow]);
  *(u16x8*)(d + (size_t)orow * R + ok) = o0;
  *(u16x8*)(d + (size_t)orow * R + ok + 8) = o1;
}

// ====================================================== 8-phase 256x256 GEMM
// BM=BN=256, BK=64, 8 waves (2Mx4N), 512 thr. LDS 128KB double-buffered.
// Swizzle byte ^= ((row&7)<<4) via inverse-swizzled GLOBAL source (linear LDS
// dest, rule 21) + swizzled ds_read offset.
// Schedule changes vs round 2 (both verified race-free under <=1-phase skew):
//  - reads issued in consumption order, NO forced lgkmcnt drain / sched_barrier
//    -> compiler emits incremental lgkmcnt, pipelining reads with MFMA
//  - ONE barrier per phase (end only) -> waves skew, LDS pipe overlaps MFMA
// Prefetch ledger unchanged: p0/p1: t1.A  p2/p3: t0'.B  p4/p5: t0'.A
// p6/p7: t1'.B ; vmcnt(4) after MFMA of p3 & p7, before that phase's barrier.

#define DSA(b, mi)                                                             \
  _Pragma("unroll") for (int m2_ = 0; m2_ < 2; ++m2_)                          \
  _Pragma("unroll") for (int ks_ = 0; ks_ < 2; ++ks_)                          \
      aF[m2_][ks_] = *(const bf16x8*)(sm + (b) * 32768 + aRowBase +            \
                                      ((mi) * 2 + m2_) * 2048 + koff[ks_]);

#define DSB(b)                                                                 \
  _Pragma("unroll") for (int n_ = 0; n_ < 4; ++n_)                             \
  _Pragma("unroll") for (int ks_ = 0; ks_ < 2; ++ks_)                          \
      bF[n_][ks_] = *(const bf16x8*)(sm + 65536 + (b) * 32768 + bRowBase +     \
                                     n_ * 2048 + koff[ks_]);

// n-outer so MFMA consumption order matches read issue order (incremental
// lgkmcnt waits from the compiler).
#define MFMA16(mi)                                                             \
  _Pragma("unroll") for (int n_ = 0; n_ < 4; ++n_)                             \
  _Pragma("unroll") for (int m2_ = 0; m2_ < 2; ++m2_)                          \
  _Pragma("unroll") for (int ks_ = 0; ks_ < 2; ++ks_)                          \
      acc[(mi) * 2 + m2_][n_] = __builtin_amdgcn_mfma_f32_16x16x32_bf16(       \
          aF[m2_][ks_], bF[n_][ks_], acc[(mi) * 2 + m2_][n_], 0, 0, 0);

#define PF_A(db, q, d) GLD16(aP[q] + (d), sm + (db) * 32768 + (q) * 8192 + tid * 16)
#define PF_B(db, q, d) GLD16(bP[q] + (d), sm + 65536 + (db) * 32768 + (q) * 8192 + tid * 16)

#define PHASE(b, mi, PFC, WTC)                                                 \
  do {                                                                         \
    DSA(b, mi);                                                                \
    if ((mi) == 0) { DSB(b); }                                                 \
    PFC                                                                        \
    __builtin_amdgcn_s_setprio(1);                                             \
    MFMA16(mi);                                                                \
    __builtin_amdgcn_s_setprio(0);                                             \
    WTC                                                                        \
    __builtin_amdgcn_s_barrier();                                              \
  } while (0)

#define KLOOP_BODY                                                             \
  /* prologue: t0 (B,A) then t1.B; wait t0 arrived, 4 loads in flight */       \
  PF_B(0, 0, 0); PF_B(0, 1, 0); PF_B(0, 2, 0); PF_B(0, 3, 0);                  \
  PF_A(0, 0, 0); PF_A(0, 1, 0); PF_A(0, 2, 0); PF_A(0, 3, 0);                  \
  PF_B(1, 0, 64); PF_B(1, 1, 64); PF_B(1, 2, 64); PF_B(1, 3, 64);              \
  asm volatile("s_waitcnt vmcnt(4)" ::: "memory");                             \
  __builtin_amdgcn_s_barrier();                                                \
  for (int it = 0; it < 7; ++it) {                                             \
    PHASE(0, 0, PF_A(1, 0, 64); PF_A(1, 1, 64);, );                            \
    PHASE(0, 1, PF_A(1, 2, 64); PF_A(1, 3, 64);, );                            \
    PHASE(0, 2, PF_B(0, 0, 128); PF_B(0, 1, 128);, );                          \
    PHASE(0, 3, PF_B(0, 2, 128); PF_B(0, 3, 128);,                             \
          asm volatile("s_waitcnt vmcnt(4)" ::: "memory"););                   \
    PHASE(1, 0, PF_A(0, 0, 128); PF_A(0, 1, 128);, );                          \
    PHASE(1, 1, PF_A(0, 2, 128); PF_A(0, 3, 128);, );                          \
    PHASE(1, 2, PF_B(1, 0, 192); PF_B(1, 1, 192);, );                          \
    PHASE(1, 3, PF_B(1, 2, 192); PF_B(1, 3, 192);,                             \
          asm volatile("s_waitcnt vmcnt(4)" ::: "memory"););                   \
    _Pragma("unroll") for (int q_ = 0; q_ < 4; ++q_) {                         \
      aP[q_] += 128; bP[q_] += 128;                                            \
    }                                                                          \
  }                                                                            \
  /* peeled last iter: only t1.A issues remain; drain fully */                 \
  PHASE(0, 0, PF_A(1, 0, 64); PF_A(1, 1, 64);, );                              \
  PHASE(0, 1, PF_A(1, 2, 64); PF_A(1, 3, 64);, );                              \
  PHASE(0, 2, , );                                                             \
  PHASE(0, 3, , asm volatile("s_waitcnt vmcnt(0)" ::: "memory"););             \
  PHASE(1, 0, , );                                                             \
  PHASE(1, 1, , );                                                             \
  PHASE(1, 2, , );                                                             \
  PHASE(1, 3, , );

// ---------------------------------------------------------------- GEMM1+GLU
__global__ __launch_bounds__(512, 2) void gemm1_8p(
    const u16* __restrict__ xbf, const u16* __restrict__ w1t,
    const float* __restrict__ b1, const float* __restrict__ probs,
    u16* __restrict__ abf) {
  extern __shared__ char sm[];
  const int tid = threadIdx.x;
  const int lane = tid & 63;
  const int wid = tid >> 6;
  const int wm = wid >> 2, wn = wid & 3;
  const int bid = blockIdx.x;
  const int e = bid & 7;          // expert -> XCD pinning (round-robin bid%8)
  const int inner = bid >> 3;
  const int mt = inner >> 3, ct = inner & 7;
  const int tokBase = e * TPE + mt * 256;
  const int c0 = ct * 128;
  const int lrow = lane & 15, lkhi = lane >> 4;

  const u16* aP[4]; const u16* bP[4];
#pragma unroll
  for (int q = 0; q < 4; ++q) {
    int lin = q * 8192 + tid * 16;
    int lg = lin ^ (((lin >> 7) & 7) << 4);   // inverse swizzle (involution)
    int row = lg >> 7, kk = (lg & 127) >> 1;
    aP[q] = xbf + (size_t)(tokBase + row) * H_DIM + kk;
    // B row nn: alternate 32-blocks gate/lin so each wave owns matching pairs
    int col = (((row >> 5) & 1) << 10) + c0 + ((row >> 6) << 5) + (row & 31);
    bP[q] = w1t + (size_t)(e * 2 * F_DIM + col) * H_DIM + kk;
  }
  const int aRowBase = (wm * 128 + lrow) * 128;
  const int bRowBase = (wn * 64 + lrow) * 128;
  int koff[2];
#pragma unroll
  for (int ks = 0; ks < 2; ++ks)
    koff[ks] = ((ks << 6) | (lkhi << 4)) ^ ((lane & 7) << 4);

  f32x4 acc[8][4];
#pragma unroll
  for (int i = 0; i < 8; ++i)
#pragma unroll
    for (int j = 0; j < 4; ++j) acc[i][j] = f32x4{0.f, 0.f, 0.f, 0.f};
  bf16x8 aF[2][2], bF[4][2];

  KLOOP_BODY

  // epilogue: a = silu(gate+b1g) * (lin+b1l+1) * p -> bf16
#pragma unroll
  for (int j = 0; j < 2; ++j) {
    int cf = c0 + wn * 32 + j * 16 + lrow;
    float gb = b1[e * 2 * F_DIM + cf];
    float lb = b1[e * 2 * F_DIM + F_DIM + cf];
#pragma unroll
    for (int i = 0; i < 8; ++i) {
      int trow = tokBase + wm * 128 + i * 16 + lkhi * 4;
#pragma unroll
      for (int r = 0; r < 4; ++r) {
        float g = acc[i][j][r] + gb;
        float l = acc[i][j + 2][r] + lb + 1.0f;
        float p = probs[trow + r];
        float sig = 1.0f / (1.0f + __expf(-g));
        abf[(size_t)(trow + r) * F_DIM + cf] = f2bf(g * sig * l * p);
      }
    }
  }
}

// ---------------------------------------------------------------- GEMM2
__global__ __launch_bounds__(512, 2) void gemm2_8p(
    const u16* __restrict__ abf, const u16* __restrict__ w2t,
    const float* __restrict__ b2, float* __restrict__ out) {
  extern __shared__ char sm[];
  const int tid = threadIdx.x;
  const int lane = tid & 63;
  const int wid = tid >> 6;
  const int wm = wid >> 2, wn = wid & 3;
  const int bid = blockIdx.x;
  const int e = bid & 7;
  const int inner = bid >> 3;
  const int mt = inner >> 2, nt = inner & 3;
  const int tokBase = e * TPE + mt * 256;
  const int h0 = nt * 256;
  const int lrow = lane & 15, lkhi = lane >> 4;

  const u16* aP[4]; const u16* bP[4];
#pragma unroll
  for (int q = 0; q < 4; ++q) {
    int lin = q * 8192 + tid * 16;
    int lg = lin ^ (((lin >> 7) & 7) << 4);
    int row = lg >> 7, kk = (lg & 127) >> 1;
    aP[q] = abf + (size_t)(tokBase + row) * F_DIM + kk;
    bP[q] = w2t + (size_t)(e * H_DIM + h0 + row) * F_DIM + kk;
  }
  const int aRowBase = (wm * 128 + lrow) * 128;
  const int bRowBase = (wn * 64 + lrow) * 128;
  int koff[2];
#pragma unroll
  for (int ks = 0; ks < 2; ++ks)
    koff[ks] = ((ks << 6) | (lkhi << 4)) ^ ((lane & 7) << 4);

  f32x4 acc[8][4];
#pragma unroll
  for (int i = 0; i < 8; ++i)
#pragma unroll
    for (int j = 0; j < 4; ++j) acc[i][j] = f32x4{0.f, 0.f, 0.f, 0.f};
  bf16x8 aF[2][2], bF[4][2];

  KLOOP_BODY

#pragma unroll
  for (int j = 0; j < 4; ++j) {
    int h = h0 + wn * 64 + j * 16 + lrow;
    float bb = b2[e * H_DIM + h];
#pragma unroll
    for (int i = 0; i < 8; ++i) {
      int trow = tokBase + wm * 128 + i * 16 + lkhi * 4;
#pragma unroll
      for (int r = 0; r < 4; ++r)
        out[(size_t)(trow + r) * H_DIM + h] = acc[i][j][r] + bb;
    }
  }
}

// ---------------------------------------------------------------- launch
extern "C" void kernel_launch(void* const* d_in, const int* in_sizes, int n_in,
                              void* d_out, int out_size, void* d_ws,
                              size_t ws_size, hipStream_t stream) {
  const float* x     = (const float*)d_in[0];
  // d_in[1] tokens_per_expert: uniform (T/E) by construction, unused
  const float* probs = (const float*)d_in[2];
  const float* W1    = (const float*)d_in[3];
  const float* b1    = (const float*)d_in[4];
  const float* W2    = (const float*)d_in[5];
  const float* b2    = (const float*)d_in[6];
  float* out = (float*)d_out;

  // workspace: xbf[T,H] 32MB | w1t[E,2F,H] 32MB | w2t[E,H,F] 16MB | abf 32MB
  if (ws_size < 117440512u) return;
  char* ws = (char*)d_ws;
  u16* xbf = (u16*)(ws);
  u16* w1t = (u16*)(ws + 33554432);
  u16* w2t = (u16*)(ws + 67108864);
  u16* abf = (u16*)(ws + 83886080);

  (void)hipFuncSetAttribute(reinterpret_cast<const void*>(gemm1_8p),
                            hipFuncAttributeMaxDynamicSharedMemorySize, 131072);
  (void)hipFuncSetAttribute(reinterpret_cast<const void*>(gemm2_8p),
                            hipFuncAttributeMaxDynamicSharedMemorySize, 131072);

  prep<<<8192, 256, 0, stream>>>(x, W1, W2, xbf, w1t, w2t);
  gemm1_8p<<<E_NUM * 8 * 8, 512, 131072, stream>>>(xbf, w1t, b1, probs, abf);
  gemm2_8p<<<E_NUM * 8 * 4, 512, 131072, stream>>>(abf, w2t, b2, out);
}